// Round 1
// baseline (794.884 us; speedup 1.0000x reference)
//
#include <hip/hip_runtime.h>
#include <hip/hip_bf16.h>

#define BATCH 4
#define S_LEN 2048
#define D_DIM 1024
#define NHEAD 16
#define HDIM 64

typedef __attribute__((ext_vector_type(8))) __bf16 bf16x8;
typedef __attribute__((ext_vector_type(4))) __bf16 bf16x4;
typedef __attribute__((ext_vector_type(4))) float f32x4;

// Load 8 consecutive fp32 and convert to bf16x8 (A/B fragment).
__device__ inline bf16x8 load_cvt8(const float* __restrict__ p) {
    const f32x4* p4 = reinterpret_cast<const f32x4*>(p);
    f32x4 a = p4[0];
    f32x4 b = p4[1];
    bf16x8 r;
    r[0] = (__bf16)a[0]; r[1] = (__bf16)a[1]; r[2] = (__bf16)a[2]; r[3] = (__bf16)a[3];
    r[4] = (__bf16)b[0]; r[5] = (__bf16)b[1]; r[6] = (__bf16)b[2]; r[7] = (__bf16)b[3];
    return r;
}

// ---------------------------------------------------------------------------
// QKV projection: Y[m][n] = sum_d x[m][d] * W[n][d]
//   m in [0, B*S), n in [0, 3*1024): matrix = n/1024 (0=q,1=k,2=v)
//   q,k written as [b][h][s][e]; v written transposed as [b][h][e][s]
// Block = 256 threads = 4 waves (2x2), wave tile 64x64, block tile 128x128.
// ---------------------------------------------------------------------------
__global__ __launch_bounds__(256) void qkv_proj_kernel(
    const float* __restrict__ x, const float* __restrict__ Wq,
    const float* __restrict__ Wk, const float* __restrict__ Wv,
    __bf16* __restrict__ qo, __bf16* __restrict__ ko, __bf16* __restrict__ vto)
{
    const int tid = threadIdx.x;
    const int l  = tid & 63;
    const int w  = tid >> 6;        // 0..3
    const int wm = w >> 1, wn = w & 1;
    const int m0 = blockIdx.y * 128 + wm * 64;
    const int n0 = blockIdx.x * 128 + wn * 64;
    const int lr = l & 15;          // A-row / B-col / D-col
    const int lg = l >> 4;          // 0..3
    const int lk = lg * 8;          // k offset within fragment

    const int mat = n0 >> 10;       // 0=q, 1=k, 2=v (block tile never crosses)
    const float* __restrict__ W = (mat == 0) ? Wq : (mat == 1) ? Wk : Wv;
    const int nb = n0 & 1023;

    f32x4 acc[4][4] = {};

    for (int d = 0; d < D_DIM; d += 32) {
        bf16x8 af[4], bfr[4];
        #pragma unroll
        for (int mi = 0; mi < 4; ++mi)
            af[mi] = load_cvt8(x + (size_t)(m0 + mi * 16 + lr) * D_DIM + d + lk);
        #pragma unroll
        for (int ni = 0; ni < 4; ++ni)
            bfr[ni] = load_cvt8(W + (size_t)(nb + ni * 16 + lr) * D_DIM + d + lk);
        #pragma unroll
        for (int mi = 0; mi < 4; ++mi) {
            #pragma unroll
            for (int ni = 0; ni < 4; ++ni)
                acc[mi][ni] = __builtin_amdgcn_mfma_f32_16x16x32_bf16(
                    af[mi], bfr[ni], acc[mi][ni], 0, 0, 0);
        }
    }

    // Write out. D layout: row = 4*lg + r, col = lr.
    #pragma unroll
    for (int mi = 0; mi < 4; ++mi) {
        const int m_base = m0 + mi * 16 + lg * 4;   // 4 consecutive rows
        const int b = m_base >> 11;                 // / S_LEN
        const int s = m_base & (S_LEN - 1);
        #pragma unroll
        for (int ni = 0; ni < 4; ++ni) {
            const int n = nb + ni * 16 + lr;
            const int h = n >> 6;
            const int e = n & 63;
            if (mat == 2) {
                // v transposed: [b][h][e][s], 4 consecutive s -> packed 8B store
                bf16x4 pk;
                #pragma unroll
                for (int r = 0; r < 4; ++r) pk[r] = (__bf16)acc[mi][ni][r];
                *reinterpret_cast<bf16x4*>(
                    vto + ((size_t)(b * NHEAD + h) * HDIM + e) * S_LEN + s) = pk;
            } else {
                __bf16* __restrict__ dst = (mat == 0) ? qo : ko;
                #pragma unroll
                for (int r = 0; r < 4; ++r)
                    dst[((size_t)(b * NHEAD + h) * S_LEN + (s + r)) * HDIM + e] =
                        (__bf16)acc[mi][ni][r];
            }
        }
    }
}

// ---------------------------------------------------------------------------
// Causal flash attention. Block = (q-tile of 64 rows) x (b*H). 4 waves,
// each wave owns 16 q rows. KV tiles of 32, online softmax in fp32.
// q,k: [bh][s][e] bf16 ; vt: [bh][e][s] bf16 ; out: [b][s][h*64+e] fp32.
// ---------------------------------------------------------------------------
__global__ __launch_bounds__(256) void attn_kernel(
    const __bf16* __restrict__ q, const __bf16* __restrict__ k,
    const __bf16* __restrict__ vt, float* __restrict__ out)
{
    __shared__ __bf16 plds[4][16][32];   // per-wave P tile (16 q x 32 kv)

    const int tid = threadIdx.x;
    const int l  = tid & 63;
    const int w  = tid >> 6;
    const int lr = l & 15;
    const int lg = l >> 4;
    const int lk = lg * 8;

    const int bh = blockIdx.y;            // b*H + h
    const int q0 = blockIdx.x * 64;
    const int qw = q0 + w * 16;           // this wave's first q row

    const __bf16* __restrict__ qp = q  + ((size_t)bh * S_LEN + qw) * HDIM;
    const __bf16* __restrict__ kp = k  + (size_t)bh * S_LEN * HDIM;
    const __bf16* __restrict__ vp = vt + (size_t)bh * HDIM * S_LEN;

    // Q fragments (A layout): row = lr, k(e) = lk + j ; two frags over e=0..63
    bf16x8 aq0 = *reinterpret_cast<const bf16x8*>(qp + lr * HDIM + lk);
    bf16x8 aq1 = *reinterpret_cast<const bf16x8*>(qp + lr * HDIM + 32 + lk);

    float m_r[4], l_r[4];
    f32x4 acco[4] = {};
    #pragma unroll
    for (int r = 0; r < 4; ++r) { m_r[r] = -1e30f; l_r[r] = 0.0f; }

    const int kv_end = q0 + 64;           // uniform across the block
    for (int kv0 = 0; kv0 < kv_end; kv0 += 32) {
        // QK^T: B layout: col(kv) = lr, k(e) = lk + j
        f32x4 s0 = {}, s1 = {};
        {
            bf16x8 b00 = *reinterpret_cast<const bf16x8*>(kp + (size_t)(kv0 + lr) * HDIM + lk);
            bf16x8 b01 = *reinterpret_cast<const bf16x8*>(kp + (size_t)(kv0 + lr) * HDIM + 32 + lk);
            bf16x8 b10 = *reinterpret_cast<const bf16x8*>(kp + (size_t)(kv0 + 16 + lr) * HDIM + lk);
            bf16x8 b11 = *reinterpret_cast<const bf16x8*>(kp + (size_t)(kv0 + 16 + lr) * HDIM + 32 + lk);
            s0 = __builtin_amdgcn_mfma_f32_16x16x32_bf16(aq0, b00, s0, 0, 0, 0);
            s0 = __builtin_amdgcn_mfma_f32_16x16x32_bf16(aq1, b01, s0, 0, 0, 0);
            s1 = __builtin_amdgcn_mfma_f32_16x16x32_bf16(aq0, b10, s1, 0, 0, 0);
            s1 = __builtin_amdgcn_mfma_f32_16x16x32_bf16(aq1, b11, s1, 0, 0, 0);
        }

        // scale + causal mask + online softmax (rows qg = qw + 4*lg + r)
        float p0[4], p1[4];
        #pragma unroll
        for (int r = 0; r < 4; ++r) {
            const int qg = qw + lg * 4 + r;
            float v0 = s0[r] * 0.125f;
            float v1 = s1[r] * 0.125f;
            if (kv0 + lr > qg)      v0 = -1e30f;
            if (kv0 + 16 + lr > qg) v1 = -1e30f;
            float mx = fmaxf(v0, v1);
            #pragma unroll
            for (int sft = 1; sft < 16; sft <<= 1)
                mx = fmaxf(mx, __shfl_xor(mx, sft));
            const float mnew  = fmaxf(m_r[r], mx);
            const float scale = __expf(m_r[r] - mnew);
            p0[r] = __expf(v0 - mnew);
            p1[r] = __expf(v1 - mnew);
            float rs = p0[r] + p1[r];
            #pragma unroll
            for (int sft = 1; sft < 16; sft <<= 1)
                rs += __shfl_xor(rs, sft);
            l_r[r] = l_r[r] * scale + rs;
            m_r[r] = mnew;
            #pragma unroll
            for (int ni = 0; ni < 4; ++ni)
                acco[ni][r] *= scale;
        }

        // P tile to LDS (D layout -> memory), then read back in A layout
        #pragma unroll
        for (int r = 0; r < 4; ++r) {
            plds[w][lg * 4 + r][lr]      = (__bf16)p0[r];
            plds[w][lg * 4 + r][16 + lr] = (__bf16)p1[r];
        }
        __syncthreads();

        bf16x8 pa = *reinterpret_cast<const bf16x8*>(&plds[w][lr][lk]);
        #pragma unroll
        for (int ni = 0; ni < 4; ++ni) {
            bf16x8 bv = *reinterpret_cast<const bf16x8*>(
                vp + (size_t)(ni * 16 + lr) * S_LEN + kv0 + lk);
            acco[ni] = __builtin_amdgcn_mfma_f32_16x16x32_bf16(pa, bv, acco[ni], 0, 0, 0);
        }
        __syncthreads();
    }

    // Epilogue: out[b][s][h*64 + e] = acc/l
    const int bq = bh >> 4;
    const int hq = bh & 15;
    #pragma unroll
    for (int ni = 0; ni < 4; ++ni) {
        #pragma unroll
        for (int r = 0; r < 4; ++r) {
            const int sq = qw + lg * 4 + r;
            const int e  = ni * 16 + lr;
            out[(size_t)(bq * S_LEN + sq) * D_DIM + hq * HDIM + e] =
                acco[ni][r] / l_r[r];
        }
    }
}

extern "C" void kernel_launch(void* const* d_in, const int* in_sizes, int n_in,
                              void* d_out, int out_size, void* d_ws, size_t ws_size,
                              hipStream_t stream)
{
    const float* x  = (const float*)d_in[0];
    const float* Wq = (const float*)d_in[1];
    const float* Wk = (const float*)d_in[2];
    const float* Wv = (const float*)d_in[3];
    float* out = (float*)d_out;

    const size_t per_buf = (size_t)BATCH * NHEAD * S_LEN * HDIM;  // 8.4M elems
    __bf16* qb = (__bf16*)d_ws;
    __bf16* kb = qb + per_buf;
    __bf16* vb = kb + per_buf;

    dim3 grid1(3 * D_DIM / 128, (BATCH * S_LEN) / 128);   // (24, 64)
    qkv_proj_kernel<<<grid1, dim3(256), 0, stream>>>(x, Wq, Wk, Wv, qb, kb, vb);

    dim3 grid2(S_LEN / 64, BATCH * NHEAD);                // (32, 64)
    attn_kernel<<<grid2, dim3(256), 0, stream>>>(qb, kb, vb, out);
}

// Round 2
// 343.936 us; speedup vs baseline: 2.3111x; 2.3111x over previous
//
#include <hip/hip_runtime.h>
#include <hip/hip_bf16.h>

#define BATCH 4
#define S_LEN 2048
#define D_DIM 1024
#define NHEAD 16
#define HDIM 64

typedef __attribute__((ext_vector_type(8))) __bf16 bf16x8;
typedef __attribute__((ext_vector_type(4))) __bf16 bf16x4;
typedef __attribute__((ext_vector_type(4))) float f32x4;

static __device__ inline unsigned short bf16_bits(float f) {
    __bf16 h = (__bf16)f;
    return __builtin_bit_cast(unsigned short, h);
}

// ---------------------------------------------------------------------------
// fp32 -> bf16 bulk convert, 8 elems/thread, 16B stores.
// ---------------------------------------------------------------------------
__global__ __launch_bounds__(256) void cvt_kernel(
    const float* __restrict__ src, __bf16* __restrict__ dst, int n8)
{
    int i = blockIdx.x * 256 + threadIdx.x;
    if (i >= n8) return;
    const f32x4* p = reinterpret_cast<const f32x4*>(src + (size_t)i * 8);
    f32x4 a = p[0], b = p[1];
    bf16x8 r;
    r[0] = (__bf16)a[0]; r[1] = (__bf16)a[1]; r[2] = (__bf16)a[2]; r[3] = (__bf16)a[3];
    r[4] = (__bf16)b[0]; r[5] = (__bf16)b[1]; r[6] = (__bf16)b[2]; r[7] = (__bf16)b[3];
    *reinterpret_cast<bf16x8*>(dst + (size_t)i * 8) = r;
}

// ---------------------------------------------------------------------------
// Projection GEMM (m97-style): C[m][n] = sum_d xb[m][d] * wb[n][d]
// xb: [8192][1024] bf16, wb: [3072][1024] bf16 (q rows 0-1023, k, v).
// BM=BN=128, BK=32, 256 thr / 4 waves (2x2), wave tile 64x64 (4x4 frags).
// global_load_lds width-16 staging; q,k -> [bh][s][e]; v -> [bh][e][s].
// ---------------------------------------------------------------------------
__global__ __launch_bounds__(256) void proj_gemm_kernel(
    const __bf16* __restrict__ xb, const __bf16* __restrict__ wb,
    __bf16* __restrict__ qo, __bf16* __restrict__ ko, __bf16* __restrict__ vto)
{
    __shared__ __bf16 As[128][32];
    __shared__ __bf16 Bs[128][32];

    const int tid = threadIdx.x;
    const int l  = tid & 63;
    const int w  = tid >> 6;
    const int wm = w >> 1, wn = w & 1;
    const int lr = l & 15, lg = l >> 4, lk = lg * 8;
    const int m0 = blockIdx.y * 128;
    const int n0 = blockIdx.x * 128;
    const int mat = n0 >> 10;           // 0=q,1=k,2=v
    const int nb  = n0 & 1023;

    // staging: wave w stages LDS rows [w*32, w*32+32) of As and Bs.
    // lane l covers row g*16 + l/4, col bytes (l%4)*16 (dest = base + l*16).
    const int sr = l >> 2;
    const int sc = (l & 3) * 8;
    const int g0 = w * 2;

    f32x4 acc[4][4] = {};

    for (int d = 0; d < D_DIM; d += 32) {
        __builtin_amdgcn_global_load_lds(
            (const __attribute__((address_space(1))) void*)(xb + (size_t)(m0 + g0 * 16 + sr) * D_DIM + d + sc),
            (__attribute__((address_space(3))) void*)(&As[g0 * 16][0]), 16, 0, 0);
        __builtin_amdgcn_global_load_lds(
            (const __attribute__((address_space(1))) void*)(xb + (size_t)(m0 + (g0 + 1) * 16 + sr) * D_DIM + d + sc),
            (__attribute__((address_space(3))) void*)(&As[(g0 + 1) * 16][0]), 16, 0, 0);
        __builtin_amdgcn_global_load_lds(
            (const __attribute__((address_space(1))) void*)(wb + (size_t)(n0 + g0 * 16 + sr) * D_DIM + d + sc),
            (__attribute__((address_space(3))) void*)(&Bs[g0 * 16][0]), 16, 0, 0);
        __builtin_amdgcn_global_load_lds(
            (const __attribute__((address_space(1))) void*)(wb + (size_t)(n0 + (g0 + 1) * 16 + sr) * D_DIM + d + sc),
            (__attribute__((address_space(3))) void*)(&Bs[(g0 + 1) * 16][0]), 16, 0, 0);
        __syncthreads();

        bf16x8 af[4], bfr[4];
        #pragma unroll
        for (int mi = 0; mi < 4; ++mi)
            af[mi] = *reinterpret_cast<const bf16x8*>(&As[wm * 64 + mi * 16 + lr][lk]);
        #pragma unroll
        for (int ni = 0; ni < 4; ++ni)
            bfr[ni] = *reinterpret_cast<const bf16x8*>(&Bs[wn * 64 + ni * 16 + lr][lk]);
        #pragma unroll
        for (int mi = 0; mi < 4; ++mi) {
            #pragma unroll
            for (int ni = 0; ni < 4; ++ni)
                acc[mi][ni] = __builtin_amdgcn_mfma_f32_16x16x32_bf16(
                    af[mi], bfr[ni], acc[mi][ni], 0, 0, 0);
        }
        __syncthreads();
    }

    // Epilogue. D layout: row = 4*lg + r, col = lr.
    #pragma unroll
    for (int mi = 0; mi < 4; ++mi) {
        const int mrow = m0 + wm * 64 + mi * 16 + lg * 4;
        const int b = mrow >> 11;
        const int s = mrow & (S_LEN - 1);
        #pragma unroll
        for (int ni = 0; ni < 4; ++ni) {
            const int n = nb + wn * 64 + ni * 16 + lr;
            const int h = n >> 6;
            const int e = n & 63;
            if (mat == 2) {
                bf16x4 pk;
                #pragma unroll
                for (int r = 0; r < 4; ++r) pk[r] = (__bf16)acc[mi][ni][r];
                *reinterpret_cast<bf16x4*>(
                    vto + ((size_t)(b * NHEAD + h) * HDIM + e) * S_LEN + s) = pk;
            } else {
                __bf16* __restrict__ dst = (mat == 0) ? qo : ko;
                #pragma unroll
                for (int r = 0; r < 4; ++r)
                    dst[((size_t)(b * NHEAD + h) * S_LEN + (s + r)) * HDIM + e] =
                        (__bf16)acc[mi][ni][r];
            }
        }
    }
}

// ---------------------------------------------------------------------------
// Causal flash attention, swapped-QK^T layout, barrier-free (wave-local LDS).
// Per wave: 16 q rows, KV tiles of 64. QK^T = mfma(K, Q) so each lane holds
// 16 P-values of ONE q-row (q = qw + lane&15) -> softmax = in-reg + 2 shfl.
// P transposed to A-layout through XOR-swizzled wave-local LDS.
// Block pairs q-tiles (t, 31-t) for uniform work; XCD swizzle: 8 heads/XCD.
// ---------------------------------------------------------------------------
__global__ __launch_bounds__(256) void attn_kernel(
    const __bf16* __restrict__ q, const __bf16* __restrict__ k,
    const __bf16* __restrict__ vt, float* __restrict__ out)
{
    __shared__ __bf16 plds[4][16][64];   // per-wave P tile (16 q x 64 kv)

    const int tid = threadIdx.x;
    const int l  = tid & 63;
    const int w  = tid >> 6;
    const int lr = l & 15;
    const int lg = l >> 4;
    const int lk = lg * 8;
    const int swz = (lr & 7) << 3;       // XOR swizzle for P columns

    // block remap: n = by*16+bx ; xcd = n&7 owns heads [xcd*8, xcd*8+8)
    const int n   = blockIdx.y * 16 + blockIdx.x;
    const int xcd = n & 7;
    const int idx = n >> 3;
    const int bh  = xcd * 8 + (idx >> 4);
    const int tp  = idx & 15;            // tile-pair index

    const __bf16* __restrict__ kp = k  + (size_t)bh * S_LEN * HDIM;
    const __bf16* __restrict__ vp = vt + (size_t)bh * HDIM * S_LEN;
    const int bq = bh >> 4;
    const int hq = bh & 15;

    #pragma unroll 1
    for (int pi = 0; pi < 2; ++pi) {
        const int q0 = (pi ? (31 - tp) : tp) * 64;
        const int qw = q0 + w * 16;

        const __bf16* __restrict__ qp = q + ((size_t)bh * S_LEN + qw) * HDIM;
        // Q B-fragments: col = lr (q row), k = lk+j (e)
        const bf16x8 bq0 = *reinterpret_cast<const bf16x8*>(qp + lr * HDIM + lk);
        const bf16x8 bq1 = *reinterpret_cast<const bf16x8*>(qp + lr * HDIM + 32 + lk);

        float m_acc = -1e30f, l_acc = 0.0f;
        f32x4 acco[4] = {};

        for (int kv0 = 0; kv0 < q0 + 64; kv0 += 64) {
            // ---- QK^T (swapped): s[c] = K[kv-sub c] x Q ----
            f32x4 s[4];
            #pragma unroll
            for (int c = 0; c < 4; ++c) {
                const __bf16* krow = kp + (size_t)(kv0 + c * 16 + lr) * HDIM;
                bf16x8 ka0 = *reinterpret_cast<const bf16x8*>(krow + lk);
                bf16x8 ka1 = *reinterpret_cast<const bf16x8*>(krow + 32 + lk);
                f32x4 t = {};
                t = __builtin_amdgcn_mfma_f32_16x16x32_bf16(ka0, bq0, t, 0, 0, 0);
                t = __builtin_amdgcn_mfma_f32_16x16x32_bf16(ka1, bq1, t, 0, 0, 0);
                s[c] = t;
            }

            // ---- scale + causal mask (lane's q row = qw + lr) ----
            float v[4][4];
            #pragma unroll
            for (int c = 0; c < 4; ++c)
                #pragma unroll
                for (int r = 0; r < 4; ++r)
                    v[c][r] = s[c][r] * 0.125f;
            if (kv0 + 63 > qw) {               // wave-uniform branch
                const int qrow = qw + lr;
                #pragma unroll
                for (int c = 0; c < 4; ++c)
                    #pragma unroll
                    for (int r = 0; r < 4; ++r)
                        if (kv0 + c * 16 + lg * 4 + r > qrow) v[c][r] = -1e30f;
            }

            // ---- online softmax: in-reg reduce + 2 shfl ----
            float mx = v[0][0];
            #pragma unroll
            for (int c = 0; c < 4; ++c)
                #pragma unroll
                for (int r = 0; r < 4; ++r) mx = fmaxf(mx, v[c][r]);
            mx = fmaxf(mx, __shfl_xor(mx, 16));
            mx = fmaxf(mx, __shfl_xor(mx, 32));
            const float mnew  = fmaxf(m_acc, mx);
            const float scalef = __expf(m_acc - mnew);
            float p[4][4];
            float psum = 0.0f;
            #pragma unroll
            for (int c = 0; c < 4; ++c)
                #pragma unroll
                for (int r = 0; r < 4; ++r) {
                    p[c][r] = __expf(v[c][r] - mnew);
                    psum += p[c][r];
                }
            psum += __shfl_xor(psum, 16);
            psum += __shfl_xor(psum, 32);
            l_acc = l_acc * scalef + psum;
            m_acc = mnew;

            // ---- rescale acco (rows q = qw + 4*lg + r; fetch that row's scale) ----
            #pragma unroll
            for (int r = 0; r < 4; ++r) {
                const float sq = __shfl(scalef, (l & 48) | (((l >> 4) << 2) + r));
                #pragma unroll
                for (int ni = 0; ni < 4; ++ni) acco[ni][r] *= sq;
            }

            // ---- P -> LDS (swizzled), packed pairs ----
            #pragma unroll
            for (int c = 0; c < 4; ++c) {
                #pragma unroll
                for (int rp = 0; rp < 4; rp += 2) {
                    const int col = c * 16 + lg * 4 + rp;
                    const unsigned int pk =
                        (unsigned int)bf16_bits(p[c][rp]) |
                        ((unsigned int)bf16_bits(p[c][rp + 1]) << 16);
                    *reinterpret_cast<unsigned int*>(&plds[w][lr][col ^ swz]) = pk;
                }
            }

            // ---- PV: pa = P A-frags from LDS, bv = V^T B-frags from global ----
            #pragma unroll
            for (int c2 = 0; c2 < 2; ++c2) {
                const bf16x8 pa = *reinterpret_cast<const bf16x8*>(
                    &plds[w][lr][(c2 * 32 + lk) ^ swz]);
                #pragma unroll
                for (int ni = 0; ni < 4; ++ni) {
                    const bf16x8 bv = *reinterpret_cast<const bf16x8*>(
                        vp + (size_t)(ni * 16 + lr) * S_LEN + kv0 + c2 * 32 + lk);
                    acco[ni] = __builtin_amdgcn_mfma_f32_16x16x32_bf16(pa, bv, acco[ni], 0, 0, 0);
                }
            }
        }

        // ---- epilogue: rows q = qw + 4*lg + r ----
        float linv[4];
        #pragma unroll
        for (int r = 0; r < 4; ++r) {
            const float ls = __shfl(l_acc, (l & 48) | (((l >> 4) << 2) + r));
            linv[r] = 1.0f / ls;
        }
        #pragma unroll
        for (int ni = 0; ni < 4; ++ni) {
            #pragma unroll
            for (int r = 0; r < 4; ++r) {
                const int sq = qw + lg * 4 + r;
                const int e  = ni * 16 + lr;
                out[(size_t)(bq * S_LEN + sq) * D_DIM + hq * HDIM + e] =
                    acco[ni][r] * linv[r];
            }
        }
    }
}

extern "C" void kernel_launch(void* const* d_in, const int* in_sizes, int n_in,
                              void* d_out, int out_size, void* d_ws, size_t ws_size,
                              hipStream_t stream)
{
    const float* x  = (const float*)d_in[0];
    const float* Wq = (const float*)d_in[1];
    const float* Wk = (const float*)d_in[2];
    const float* Wv = (const float*)d_in[3];
    float* out = (float*)d_out;

    // bf16 scratch: x_bf16 and Wcat live in d_out (overwritten by attention
    // at the end); q/k/v live in d_ws.
    const size_t x_elems = (size_t)BATCH * S_LEN * D_DIM;       // 8.39M
    const size_t w_elems = (size_t)D_DIM * D_DIM;               // 1.05M per matrix
    __bf16* xb   = (__bf16*)d_out;
    __bf16* wcat = xb + x_elems;                                // 3 x w_elems

    const size_t per_buf = (size_t)BATCH * NHEAD * S_LEN * HDIM;
    __bf16* qb = (__bf16*)d_ws;
    __bf16* kb = qb + per_buf;
    __bf16* vb = kb + per_buf;

    // converts
    cvt_kernel<<<(int)(x_elems / 8 / 256), 256, 0, stream>>>(x, xb, (int)(x_elems / 8));
    cvt_kernel<<<(int)(w_elems / 8 / 256), 256, 0, stream>>>(Wq, wcat, (int)(w_elems / 8));
    cvt_kernel<<<(int)(w_elems / 8 / 256), 256, 0, stream>>>(Wk, wcat + w_elems, (int)(w_elems / 8));
    cvt_kernel<<<(int)(w_elems / 8 / 256), 256, 0, stream>>>(Wv, wcat + 2 * w_elems, (int)(w_elems / 8));

    // projection GEMM: [8192 x 3072] = xb @ wcat^T
    dim3 grid1(3 * D_DIM / 128, (BATCH * S_LEN) / 128);   // (24, 64)
    proj_gemm_kernel<<<grid1, dim3(256), 0, stream>>>(xb, wcat, qb, kb, vb);

    // attention: 16 tile-pairs x 64 heads
    dim3 grid2(16, 64);
    attn_kernel<<<grid2, dim3(256), 0, stream>>>(qb, kb, vb, out);
}

// Round 3
// 295.926 us; speedup vs baseline: 2.6861x; 1.1622x over previous
//
#include <hip/hip_runtime.h>
#include <hip/hip_bf16.h>

#define BATCH 4
#define S_LEN 2048
#define D_DIM 1024
#define NHEAD 16
#define HDIM 64

typedef __attribute__((ext_vector_type(8))) __bf16 bf16x8;
typedef __attribute__((ext_vector_type(4))) __bf16 bf16x4;
typedef __attribute__((ext_vector_type(4))) float f32x4;

static __device__ inline unsigned short bf16_bits(float f) {
    __bf16 h = (__bf16)f;
    return __builtin_bit_cast(unsigned short, h);
}

// ---------------------------------------------------------------------------
// fp32 -> bf16 bulk convert, 8 elems/thread, 16B stores.
// ---------------------------------------------------------------------------
__global__ __launch_bounds__(256) void cvt_kernel(
    const float* __restrict__ src, __bf16* __restrict__ dst, int n8)
{
    int i = blockIdx.x * 256 + threadIdx.x;
    if (i >= n8) return;
    const f32x4* p = reinterpret_cast<const f32x4*>(src + (size_t)i * 8);
    f32x4 a = p[0], b = p[1];
    bf16x8 r;
    r[0] = (__bf16)a[0]; r[1] = (__bf16)a[1]; r[2] = (__bf16)a[2]; r[3] = (__bf16)a[3];
    r[4] = (__bf16)b[0]; r[5] = (__bf16)b[1]; r[6] = (__bf16)b[2]; r[7] = (__bf16)b[3];
    *reinterpret_cast<bf16x8*>(dst + (size_t)i * 8) = r;
}

// ---------------------------------------------------------------------------
// Projection GEMM (m97-style): C[m][n] = sum_d xb[m][d] * wb[n][d]
// xb: [8192][1024] bf16, wb: [3072][1024] bf16 (q rows 0-1023, k, v).
// BM=BN=128, BK=32, 256 thr / 4 waves (2x2), wave tile 64x64 (4x4 frags).
// global_load_lds width-16 staging; q,k -> [bh][s][e]; v -> [bh][e][s].
// ---------------------------------------------------------------------------
__global__ __launch_bounds__(256) void proj_gemm_kernel(
    const __bf16* __restrict__ xb, const __bf16* __restrict__ wb,
    __bf16* __restrict__ qo, __bf16* __restrict__ ko, __bf16* __restrict__ vto)
{
    __shared__ __bf16 As[128][32];
    __shared__ __bf16 Bs[128][32];

    const int tid = threadIdx.x;
    const int l  = tid & 63;
    const int w  = tid >> 6;
    const int wm = w >> 1, wn = w & 1;
    const int lr = l & 15, lg = l >> 4, lk = lg * 8;
    const int m0 = blockIdx.y * 128;
    const int n0 = blockIdx.x * 128;
    const int mat = n0 >> 10;           // 0=q,1=k,2=v
    const int nb  = n0 & 1023;

    const int sr = l >> 2;
    const int sc = (l & 3) * 8;
    const int g0 = w * 2;

    f32x4 acc[4][4] = {};

    for (int d = 0; d < D_DIM; d += 32) {
        __builtin_amdgcn_global_load_lds(
            (const __attribute__((address_space(1))) void*)(xb + (size_t)(m0 + g0 * 16 + sr) * D_DIM + d + sc),
            (__attribute__((address_space(3))) void*)(&As[g0 * 16][0]), 16, 0, 0);
        __builtin_amdgcn_global_load_lds(
            (const __attribute__((address_space(1))) void*)(xb + (size_t)(m0 + (g0 + 1) * 16 + sr) * D_DIM + d + sc),
            (__attribute__((address_space(3))) void*)(&As[(g0 + 1) * 16][0]), 16, 0, 0);
        __builtin_amdgcn_global_load_lds(
            (const __attribute__((address_space(1))) void*)(wb + (size_t)(n0 + g0 * 16 + sr) * D_DIM + d + sc),
            (__attribute__((address_space(3))) void*)(&Bs[g0 * 16][0]), 16, 0, 0);
        __builtin_amdgcn_global_load_lds(
            (const __attribute__((address_space(1))) void*)(wb + (size_t)(n0 + (g0 + 1) * 16 + sr) * D_DIM + d + sc),
            (__attribute__((address_space(3))) void*)(&Bs[(g0 + 1) * 16][0]), 16, 0, 0);
        __syncthreads();

        bf16x8 af[4], bfr[4];
        #pragma unroll
        for (int mi = 0; mi < 4; ++mi)
            af[mi] = *reinterpret_cast<const bf16x8*>(&As[wm * 64 + mi * 16 + lr][lk]);
        #pragma unroll
        for (int ni = 0; ni < 4; ++ni)
            bfr[ni] = *reinterpret_cast<const bf16x8*>(&Bs[wn * 64 + ni * 16 + lr][lk]);
        #pragma unroll
        for (int mi = 0; mi < 4; ++mi) {
            #pragma unroll
            for (int ni = 0; ni < 4; ++ni)
                acc[mi][ni] = __builtin_amdgcn_mfma_f32_16x16x32_bf16(
                    af[mi], bfr[ni], acc[mi][ni], 0, 0, 0);
        }
        __syncthreads();
    }

    #pragma unroll
    for (int mi = 0; mi < 4; ++mi) {
        const int mrow = m0 + wm * 64 + mi * 16 + lg * 4;
        const int b = mrow >> 11;
        const int s = mrow & (S_LEN - 1);
        #pragma unroll
        for (int ni = 0; ni < 4; ++ni) {
            const int n = nb + wn * 64 + ni * 16 + lr;
            const int h = n >> 6;
            const int e = n & 63;
            if (mat == 2) {
                bf16x4 pk;
                #pragma unroll
                for (int r = 0; r < 4; ++r) pk[r] = (__bf16)acc[mi][ni][r];
                *reinterpret_cast<bf16x4*>(
                    vto + ((size_t)(b * NHEAD + h) * HDIM + e) * S_LEN + s) = pk;
            } else {
                __bf16* __restrict__ dst = (mat == 0) ? qo : ko;
                #pragma unroll
                for (int r = 0; r < 4; ++r)
                    dst[((size_t)(b * NHEAD + h) * S_LEN + (s + r)) * HDIM + e] =
                        (__bf16)acc[mi][ni][r];
            }
        }
    }
}

// ---------------------------------------------------------------------------
// Online-softmax step for one 16q x 64kv tile (swapped-QK layout).
// s[c][r] = scores for kv = kv0 + c*16 + lg*4 + r, q-row = qw + lr.
// Updates m/l/acc, writes bf16 P (A-layout-transposable) into pl (row stride
// 64, XOR-swizzled by swz). Fully-masked tiles degenerate safely (scale=1).
// ---------------------------------------------------------------------------
static __device__ inline void sm_step(
    const f32x4 s[4], int kv0, int qw, int lr, int lg, int l,
    float& m_acc, float& l_acc, f32x4 acc[4], __bf16* pl, int swz)
{
    float v[4][4];
    #pragma unroll
    for (int c = 0; c < 4; ++c)
        #pragma unroll
        for (int r = 0; r < 4; ++r)
            v[c][r] = s[c][r] * 0.125f;
    if (kv0 + 63 > qw) {                   // wave-uniform
        const int qrow = qw + lr;
        #pragma unroll
        for (int c = 0; c < 4; ++c)
            #pragma unroll
            for (int r = 0; r < 4; ++r)
                if (kv0 + c * 16 + lg * 4 + r > qrow) v[c][r] = -1e30f;
    }

    float m01 = fmaxf(fmaxf(fmaxf(v[0][0], v[0][1]), fmaxf(v[0][2], v[0][3])),
                      fmaxf(fmaxf(v[1][0], v[1][1]), fmaxf(v[1][2], v[1][3])));
    float m23 = fmaxf(fmaxf(fmaxf(v[2][0], v[2][1]), fmaxf(v[2][2], v[2][3])),
                      fmaxf(fmaxf(v[3][0], v[3][1]), fmaxf(v[3][2], v[3][3])));
    float mx = fmaxf(m01, m23);
    mx = fmaxf(mx, __shfl_xor(mx, 16));
    mx = fmaxf(mx, __shfl_xor(mx, 32));

    const float mnew  = fmaxf(m_acc, mx);
    const float scalef = __expf(m_acc - mnew);
    float p[4][4];
    float psum = 0.0f;
    #pragma unroll
    for (int c = 0; c < 4; ++c)
        #pragma unroll
        for (int r = 0; r < 4; ++r) {
            p[c][r] = __expf(v[c][r] - mnew);
            psum += p[c][r];
        }
    psum += __shfl_xor(psum, 16);
    psum += __shfl_xor(psum, 32);
    l_acc = l_acc * scalef + psum;
    m_acc = mnew;

    #pragma unroll
    for (int r = 0; r < 4; ++r) {
        const float sq = __shfl(scalef, (l & 48) | (lg * 4 + r));
        #pragma unroll
        for (int ni = 0; ni < 4; ++ni) acc[ni][r] *= sq;
    }

    #pragma unroll
    for (int c = 0; c < 4; ++c) {
        #pragma unroll
        for (int rp = 0; rp < 4; rp += 2) {
            const int col = c * 16 + lg * 4 + rp;
            const unsigned int pk =
                (unsigned int)bf16_bits(p[c][rp]) |
                ((unsigned int)bf16_bits(p[c][rp + 1]) << 16);
            *reinterpret_cast<unsigned int*>(pl + lr * 64 + (col ^ swz)) = pk;
        }
    }
}

// ---------------------------------------------------------------------------
// Causal flash attention, swapped-QK^T, barrier-free, PAIR-INTERLEAVED:
// each block processes q-tiles (2t, 2t+1) concurrently in one branchless KV
// loop; K and V fragment loads are shared by both tiles (2x MFMA per load,
// 2 independent softmax chains for ILP). 1 wasted (fully-masked) X-iter.
// ---------------------------------------------------------------------------
__global__ __launch_bounds__(256) void attn_kernel(
    const __bf16* __restrict__ q, const __bf16* __restrict__ k,
    const __bf16* __restrict__ vt, float* __restrict__ out)
{
    __shared__ __bf16 plds[4][2][16][64];   // per-wave, per-tile P

    const int tid = threadIdx.x;
    const int l  = tid & 63;
    const int w  = tid >> 6;
    const int lr = l & 15;
    const int lg = l >> 4;
    const int lk = lg * 8;
    const int swz = (lr & 7) << 3;

    const int n   = blockIdx.y * 16 + blockIdx.x;
    const int xcd = n & 7;
    const int idx = n >> 3;
    const int bh  = xcd * 8 + (idx >> 4);
    const int tp  = idx & 15;               // pair index: tiles 2tp, 2tp+1

    const __bf16* __restrict__ kp = k  + (size_t)bh * S_LEN * HDIM;
    const __bf16* __restrict__ vp = vt + (size_t)bh * HDIM * S_LEN;
    const int bq = bh >> 4;
    const int hq = bh & 15;

    const int q0x = tp * 128;
    const int qwx = q0x + w * 16;
    const int qwy = qwx + 64;

    const __bf16* __restrict__ qpx = q + ((size_t)bh * S_LEN + qwx) * HDIM;
    const bf16x8 bqX0 = *reinterpret_cast<const bf16x8*>(qpx + lr * HDIM + lk);
    const bf16x8 bqX1 = *reinterpret_cast<const bf16x8*>(qpx + lr * HDIM + 32 + lk);
    const bf16x8 bqY0 = *reinterpret_cast<const bf16x8*>(qpx + (size_t)64 * HDIM + lr * HDIM + lk);
    const bf16x8 bqY1 = *reinterpret_cast<const bf16x8*>(qpx + (size_t)64 * HDIM + lr * HDIM + 32 + lk);

    float mX = -1e30f, lX = 0.0f, mY = -1e30f, lY = 0.0f;
    f32x4 accX[4] = {}, accY[4] = {};

    __bf16* plX = &plds[w][0][0][0];
    __bf16* plY = &plds[w][1][0][0];

    const int iters = 2 * tp + 2;
    for (int j = 0; j < iters; ++j) {
        const int kv0 = j * 64;

        // ---- QK^T both tiles (shared K fragments) ----
        f32x4 sX[4], sY[4];
        __builtin_amdgcn_s_setprio(1);
        #pragma unroll
        for (int c = 0; c < 4; ++c) {
            const __bf16* krow = kp + (size_t)(kv0 + c * 16 + lr) * HDIM;
            const bf16x8 ka0 = *reinterpret_cast<const bf16x8*>(krow + lk);
            const bf16x8 ka1 = *reinterpret_cast<const bf16x8*>(krow + 32 + lk);
            f32x4 tx = {}, ty = {};
            tx = __builtin_amdgcn_mfma_f32_16x16x32_bf16(ka0, bqX0, tx, 0, 0, 0);
            tx = __builtin_amdgcn_mfma_f32_16x16x32_bf16(ka1, bqX1, tx, 0, 0, 0);
            ty = __builtin_amdgcn_mfma_f32_16x16x32_bf16(ka0, bqY0, ty, 0, 0, 0);
            ty = __builtin_amdgcn_mfma_f32_16x16x32_bf16(ka1, bqY1, ty, 0, 0, 0);
            sX[c] = tx; sY[c] = ty;
        }
        __builtin_amdgcn_s_setprio(0);

        // ---- two independent online-softmax chains ----
        sm_step(sX, kv0, qwx, lr, lg, l, mX, lX, accX, plX, swz);
        sm_step(sY, kv0, qwy, lr, lg, l, mY, lY, accY, plY, swz);

        // ---- PV both tiles (shared V fragments) ----
        __builtin_amdgcn_s_setprio(1);
        #pragma unroll
        for (int c2 = 0; c2 < 2; ++c2) {
            const bf16x8 paX = *reinterpret_cast<const bf16x8*>(
                plX + lr * 64 + ((c2 * 32 + lk) ^ swz));
            const bf16x8 paY = *reinterpret_cast<const bf16x8*>(
                plY + lr * 64 + ((c2 * 32 + lk) ^ swz));
            #pragma unroll
            for (int ni = 0; ni < 4; ++ni) {
                const bf16x8 bv = *reinterpret_cast<const bf16x8*>(
                    vp + (size_t)(ni * 16 + lr) * S_LEN + kv0 + c2 * 32 + lk);
                accX[ni] = __builtin_amdgcn_mfma_f32_16x16x32_bf16(paX, bv, accX[ni], 0, 0, 0);
                accY[ni] = __builtin_amdgcn_mfma_f32_16x16x32_bf16(paY, bv, accY[ni], 0, 0, 0);
            }
        }
        __builtin_amdgcn_s_setprio(0);
    }

    // ---- epilogue, both tiles: rows q = qw + 4*lg + r ----
    float livX[4], livY[4];
    #pragma unroll
    for (int r = 0; r < 4; ++r) {
        livX[r] = 1.0f / __shfl(lX, (l & 48) | (lg * 4 + r));
        livY[r] = 1.0f / __shfl(lY, (l & 48) | (lg * 4 + r));
    }
    #pragma unroll
    for (int ni = 0; ni < 4; ++ni) {
        #pragma unroll
        for (int r = 0; r < 4; ++r) {
            const int e = ni * 16 + lr;
            const int sqx = qwx + lg * 4 + r;
            out[(size_t)(bq * S_LEN + sqx) * D_DIM + hq * HDIM + e] =
                accX[ni][r] * livX[r];
            const int sqy = qwy + lg * 4 + r;
            out[(size_t)(bq * S_LEN + sqy) * D_DIM + hq * HDIM + e] =
                accY[ni][r] * livY[r];
        }
    }
}

extern "C" void kernel_launch(void* const* d_in, const int* in_sizes, int n_in,
                              void* d_out, int out_size, void* d_ws, size_t ws_size,
                              hipStream_t stream)
{
    const float* x  = (const float*)d_in[0];
    const float* Wq = (const float*)d_in[1];
    const float* Wk = (const float*)d_in[2];
    const float* Wv = (const float*)d_in[3];
    float* out = (float*)d_out;

    const size_t x_elems = (size_t)BATCH * S_LEN * D_DIM;
    const size_t w_elems = (size_t)D_DIM * D_DIM;
    __bf16* xb   = (__bf16*)d_out;          // scratch in d_out (overwritten)
    __bf16* wcat = xb + x_elems;

    const size_t per_buf = (size_t)BATCH * NHEAD * S_LEN * HDIM;
    __bf16* qb = (__bf16*)d_ws;
    __bf16* kb = qb + per_buf;
    __bf16* vb = kb + per_buf;

    cvt_kernel<<<(int)(x_elems / 8 / 256), 256, 0, stream>>>(x, xb, (int)(x_elems / 8));
    cvt_kernel<<<(int)(w_elems / 8 / 256), 256, 0, stream>>>(Wq, wcat, (int)(w_elems / 8));
    cvt_kernel<<<(int)(w_elems / 8 / 256), 256, 0, stream>>>(Wk, wcat + w_elems, (int)(w_elems / 8));
    cvt_kernel<<<(int)(w_elems / 8 / 256), 256, 0, stream>>>(Wv, wcat + 2 * w_elems, (int)(w_elems / 8));

    dim3 grid1(3 * D_DIM / 128, (BATCH * S_LEN) / 128);   // (24, 64)
    proj_gemm_kernel<<<grid1, dim3(256), 0, stream>>>(xb, wcat, qb, kb, vb);

    dim3 grid2(16, 64);
    attn_kernel<<<grid2, dim3(256), 0, stream>>>(qb, kb, vb, out);
}

// Round 4
// 236.439 us; speedup vs baseline: 3.3619x; 1.2516x over previous
//
#include <hip/hip_runtime.h>
#include <hip/hip_bf16.h>

#define BATCH 4
#define S_LEN 2048
#define D_DIM 1024
#define NHEAD 16
#define HDIM 64

// Q pre-scale: 1/sqrt(HDIM) * log2(e), so softmax works in exp2 domain.
#define QSCALE 0.18033688011112042f

typedef __attribute__((ext_vector_type(8))) __bf16 bf16x8;
typedef __attribute__((ext_vector_type(4))) __bf16 bf16x4;
typedef __attribute__((ext_vector_type(4))) float f32x4;

static __device__ inline unsigned short bf16_bits(float f) {
    __bf16 h = (__bf16)f;
    return __builtin_bit_cast(unsigned short, h);
}

// ---------------------------------------------------------------------------
// fp32 -> bf16 bulk convert, 8 elems/thread, 16B stores.
// ---------------------------------------------------------------------------
__global__ __launch_bounds__(256) void cvt_kernel(
    const float* __restrict__ src, __bf16* __restrict__ dst, int n8)
{
    int i = blockIdx.x * 256 + threadIdx.x;
    if (i >= n8) return;
    const f32x4* p = reinterpret_cast<const f32x4*>(src + (size_t)i * 8);
    f32x4 a = p[0], b = p[1];
    bf16x8 r;
    r[0] = (__bf16)a[0]; r[1] = (__bf16)a[1]; r[2] = (__bf16)a[2]; r[3] = (__bf16)a[3];
    r[4] = (__bf16)b[0]; r[5] = (__bf16)b[1]; r[6] = (__bf16)b[2]; r[7] = (__bf16)b[3];
    *reinterpret_cast<bf16x8*>(dst + (size_t)i * 8) = r;
}

// ---------------------------------------------------------------------------
// Projection GEMM (m97-style): C[m][n] = sum_d xb[m][d] * wb[n][d]
// q output is pre-scaled by QSCALE. q,k -> [bh][s][e]; v -> [bh][e][s].
// ---------------------------------------------------------------------------
__global__ __launch_bounds__(256) void proj_gemm_kernel(
    const __bf16* __restrict__ xb, const __bf16* __restrict__ wb,
    __bf16* __restrict__ qo, __bf16* __restrict__ ko, __bf16* __restrict__ vto)
{
    __shared__ __bf16 As[128][32];
    __shared__ __bf16 Bs[128][32];

    const int tid = threadIdx.x;
    const int l  = tid & 63;
    const int w  = tid >> 6;
    const int wm = w >> 1, wn = w & 1;
    const int lr = l & 15, lg = l >> 4, lk = lg * 8;
    const int m0 = blockIdx.y * 128;
    const int n0 = blockIdx.x * 128;
    const int mat = n0 >> 10;           // 0=q,1=k,2=v
    const int nb  = n0 & 1023;

    const int sr = l >> 2;
    const int sc = (l & 3) * 8;
    const int g0 = w * 2;

    f32x4 acc[4][4] = {};

    for (int d = 0; d < D_DIM; d += 32) {
        __builtin_amdgcn_global_load_lds(
            (const __attribute__((address_space(1))) void*)(xb + (size_t)(m0 + g0 * 16 + sr) * D_DIM + d + sc),
            (__attribute__((address_space(3))) void*)(&As[g0 * 16][0]), 16, 0, 0);
        __builtin_amdgcn_global_load_lds(
            (const __attribute__((address_space(1))) void*)(xb + (size_t)(m0 + (g0 + 1) * 16 + sr) * D_DIM + d + sc),
            (__attribute__((address_space(3))) void*)(&As[(g0 + 1) * 16][0]), 16, 0, 0);
        __builtin_amdgcn_global_load_lds(
            (const __attribute__((address_space(1))) void*)(wb + (size_t)(n0 + g0 * 16 + sr) * D_DIM + d + sc),
            (__attribute__((address_space(3))) void*)(&Bs[g0 * 16][0]), 16, 0, 0);
        __builtin_amdgcn_global_load_lds(
            (const __attribute__((address_space(1))) void*)(wb + (size_t)(n0 + (g0 + 1) * 16 + sr) * D_DIM + d + sc),
            (__attribute__((address_space(3))) void*)(&Bs[(g0 + 1) * 16][0]), 16, 0, 0);
        __syncthreads();

        bf16x8 af[4], bfr[4];
        #pragma unroll
        for (int mi = 0; mi < 4; ++mi)
            af[mi] = *reinterpret_cast<const bf16x8*>(&As[wm * 64 + mi * 16 + lr][lk]);
        #pragma unroll
        for (int ni = 0; ni < 4; ++ni)
            bfr[ni] = *reinterpret_cast<const bf16x8*>(&Bs[wn * 64 + ni * 16 + lr][lk]);
        #pragma unroll
        for (int mi = 0; mi < 4; ++mi) {
            #pragma unroll
            for (int ni = 0; ni < 4; ++ni)
                acc[mi][ni] = __builtin_amdgcn_mfma_f32_16x16x32_bf16(
                    af[mi], bfr[ni], acc[mi][ni], 0, 0, 0);
        }
        __syncthreads();
    }

    const float oscale = (mat == 0) ? QSCALE : 1.0f;
    #pragma unroll
    for (int mi = 0; mi < 4; ++mi) {
        const int mrow = m0 + wm * 64 + mi * 16 + lg * 4;
        const int b = mrow >> 11;
        const int s = mrow & (S_LEN - 1);
        #pragma unroll
        for (int ni = 0; ni < 4; ++ni) {
            const int n = nb + wn * 64 + ni * 16 + lr;
            const int h = n >> 6;
            const int e = n & 63;
            if (mat == 2) {
                bf16x4 pk;
                #pragma unroll
                for (int r = 0; r < 4; ++r) pk[r] = (__bf16)acc[mi][ni][r];
                *reinterpret_cast<bf16x4*>(
                    vto + ((size_t)(b * NHEAD + h) * HDIM + e) * S_LEN + s) = pk;
            } else {
                __bf16* __restrict__ dst = (mat == 0) ? qo : ko;
                #pragma unroll
                for (int r = 0; r < 4; ++r)
                    dst[((size_t)(b * NHEAD + h) * S_LEN + (s + r)) * HDIM + e] =
                        (__bf16)(acc[mi][ni][r] * oscale);
            }
        }
    }
}

// ---------------------------------------------------------------------------
// Online-softmax step (exp2 domain, Q pre-scaled). Scores s[c][r] for
// kv = kv0 + c*16 + lg*4 + r, q-row = qw + lr (lane-local!). Updates m/l,
// rescales acc in place (acc col = lane's q-row, thanks to swapped PV),
// writes bf16 P into pl (row stride 64, XOR-swizzle swz).
// ---------------------------------------------------------------------------
static __device__ inline void sm_step(
    const f32x4 s[4], int kv0, int qw, int lr, int lg,
    float& m_acc, float& l_acc, f32x4 acc[4], __bf16* pl, int swz)
{
    float v[4][4];
    #pragma unroll
    for (int c = 0; c < 4; ++c)
        #pragma unroll
        for (int r = 0; r < 4; ++r)
            v[c][r] = s[c][r];
    if (kv0 + 63 > qw) {                   // wave-uniform (diagonal tile only)
        const int qrow = qw + lr;
        #pragma unroll
        for (int c = 0; c < 4; ++c)
            #pragma unroll
            for (int r = 0; r < 4; ++r)
                if (kv0 + c * 16 + lg * 4 + r > qrow) v[c][r] = -1e30f;
    }

    float m01 = fmaxf(fmaxf(fmaxf(v[0][0], v[0][1]), fmaxf(v[0][2], v[0][3])),
                      fmaxf(fmaxf(v[1][0], v[1][1]), fmaxf(v[1][2], v[1][3])));
    float m23 = fmaxf(fmaxf(fmaxf(v[2][0], v[2][1]), fmaxf(v[2][2], v[2][3])),
                      fmaxf(fmaxf(v[3][0], v[3][1]), fmaxf(v[3][2], v[3][3])));
    float mx = fmaxf(m01, m23);
    mx = fmaxf(mx, __shfl_xor(mx, 16));
    mx = fmaxf(mx, __shfl_xor(mx, 32));

    const float mnew  = fmaxf(m_acc, mx);
    const float scalef = exp2f(m_acc - mnew);
    float p[4][4];
    float psum = 0.0f;
    #pragma unroll
    for (int c = 0; c < 4; ++c)
        #pragma unroll
        for (int r = 0; r < 4; ++r) {
            p[c][r] = exp2f(v[c][r] - mnew);
            psum += p[c][r];
        }
    psum += __shfl_xor(psum, 16);
    psum += __shfl_xor(psum, 32);
    l_acc = l_acc * scalef + psum;
    m_acc = mnew;

    #pragma unroll
    for (int ni = 0; ni < 4; ++ni) acc[ni] *= scalef;   // per-lane q-row!

    #pragma unroll
    for (int c = 0; c < 4; ++c) {
        #pragma unroll
        for (int rp = 0; rp < 4; rp += 2) {
            const int col = c * 16 + lg * 4 + rp;
            const unsigned int pk =
                (unsigned int)bf16_bits(p[c][rp]) |
                ((unsigned int)bf16_bits(p[c][rp + 1]) << 16);
            *reinterpret_cast<unsigned int*>(pl + lr * 64 + (col ^ swz)) = pk;
        }
    }
}

// ---------------------------------------------------------------------------
// Causal flash attention, swapped QK^T AND swapped PV (acc col = own q-row:
// no broadcast shfls). 1-wave blocks, LPT dispatch (longest tasks first),
// heads pinned to XCDs. Task = (bh, pair tp -> q-tiles 2tp/2tp+1, wave w).
// Pair loop shares K/V loads across both tiles; final iter is Y-only.
// ---------------------------------------------------------------------------
__global__ __launch_bounds__(64, 4) void attn_kernel(
    const __bf16* __restrict__ q, const __bf16* __restrict__ k,
    const __bf16* __restrict__ vt, float* __restrict__ out)
{
    __shared__ __bf16 plds[2][16][64];

    const int l  = threadIdx.x;
    const int lr = l & 15;
    const int lg = l >> 4;
    const int lk = lg * 8;
    const int swz = (lr & 7) << 3;

    // LPT decode: first 256 blocks are all tp=15 tasks, then tp=14, ...
    const int n   = blockIdx.x;
    const int xcd = n & 7;
    const int m   = n >> 3;              // 0..511
    const int tp  = 15 - (m >> 5);
    const int r5  = m & 31;
    const int bh  = xcd * 8 + (r5 >> 2);
    const int w   = r5 & 3;

    const __bf16* __restrict__ kp = k  + (size_t)bh * S_LEN * HDIM;
    const __bf16* __restrict__ vp = vt + (size_t)bh * HDIM * S_LEN;
    const int bq = bh >> 4;
    const int hq = bh & 15;

    const int q0x = tp * 128;
    const int qwx = q0x + w * 16;
    const int qwy = qwx + 64;

    const __bf16* __restrict__ qpx = q + ((size_t)bh * S_LEN + qwx) * HDIM;
    const bf16x8 bqX0 = *reinterpret_cast<const bf16x8*>(qpx + lr * HDIM + lk);
    const bf16x8 bqX1 = *reinterpret_cast<const bf16x8*>(qpx + lr * HDIM + 32 + lk);
    const bf16x8 bqY0 = *reinterpret_cast<const bf16x8*>(qpx + (size_t)64 * HDIM + lr * HDIM + lk);
    const bf16x8 bqY1 = *reinterpret_cast<const bf16x8*>(qpx + (size_t)64 * HDIM + lr * HDIM + 32 + lk);

    float mX = -1e30f, lX = 0.0f, mY = -1e30f, lY = 0.0f;
    f32x4 accX[4] = {}, accY[4] = {};

    __bf16* plX = &plds[0][0][0];
    __bf16* plY = &plds[1][0][0];

    // ---- pair loop: X and Y share K/V fragments; X's diagonal is j=2tp ----
    const int piters = 2 * tp + 1;
    for (int j = 0; j < piters; ++j) {
        const int kv0 = j * 64;

        f32x4 sX[4], sY[4];
        __builtin_amdgcn_s_setprio(1);
        #pragma unroll
        for (int c = 0; c < 4; ++c) {
            const __bf16* krow = kp + (size_t)(kv0 + c * 16 + lr) * HDIM;
            const bf16x8 ka0 = *reinterpret_cast<const bf16x8*>(krow + lk);
            const bf16x8 ka1 = *reinterpret_cast<const bf16x8*>(krow + 32 + lk);
            f32x4 tx = {}, ty = {};
            tx = __builtin_amdgcn_mfma_f32_16x16x32_bf16(ka0, bqX0, tx, 0, 0, 0);
            tx = __builtin_amdgcn_mfma_f32_16x16x32_bf16(ka1, bqX1, tx, 0, 0, 0);
            ty = __builtin_amdgcn_mfma_f32_16x16x32_bf16(ka0, bqY0, ty, 0, 0, 0);
            ty = __builtin_amdgcn_mfma_f32_16x16x32_bf16(ka1, bqY1, ty, 0, 0, 0);
            sX[c] = tx; sY[c] = ty;
        }
        __builtin_amdgcn_s_setprio(0);

        sm_step(sX, kv0, qwx, lr, lg, mX, lX, accX, plX, swz);
        sm_step(sY, kv0, qwy, lr, lg, mY, lY, accY, plY, swz);

        __builtin_amdgcn_s_setprio(1);
        #pragma unroll
        for (int c2 = 0; c2 < 2; ++c2) {
            const bf16x8 paX = *reinterpret_cast<const bf16x8*>(
                plX + lr * 64 + ((c2 * 32 + lk) ^ swz));
            const bf16x8 paY = *reinterpret_cast<const bf16x8*>(
                plY + lr * 64 + ((c2 * 32 + lk) ^ swz));
            #pragma unroll
            for (int ni = 0; ni < 4; ++ni) {
                const bf16x8 av = *reinterpret_cast<const bf16x8*>(
                    vp + (size_t)(ni * 16 + lr) * S_LEN + kv0 + c2 * 32 + lk);
                // swapped PV: D[e][q], q = lane's lr
                accX[ni] = __builtin_amdgcn_mfma_f32_16x16x32_bf16(av, paX, accX[ni], 0, 0, 0);
                accY[ni] = __builtin_amdgcn_mfma_f32_16x16x32_bf16(av, paY, accY[ni], 0, 0, 0);
            }
        }
        __builtin_amdgcn_s_setprio(0);
    }

    // ---- Y-only diagonal iteration ----
    {
        const int kv0 = piters * 64;
        f32x4 sY[4];
        __builtin_amdgcn_s_setprio(1);
        #pragma unroll
        for (int c = 0; c < 4; ++c) {
            const __bf16* krow = kp + (size_t)(kv0 + c * 16 + lr) * HDIM;
            const bf16x8 ka0 = *reinterpret_cast<const bf16x8*>(krow + lk);
            const bf16x8 ka1 = *reinterpret_cast<const bf16x8*>(krow + 32 + lk);
            f32x4 ty = {};
            ty = __builtin_amdgcn_mfma_f32_16x16x32_bf16(ka0, bqY0, ty, 0, 0, 0);
            ty = __builtin_amdgcn_mfma_f32_16x16x32_bf16(ka1, bqY1, ty, 0, 0, 0);
            sY[c] = ty;
        }
        __builtin_amdgcn_s_setprio(0);

        sm_step(sY, kv0, qwy, lr, lg, mY, lY, accY, plY, swz);

        __builtin_amdgcn_s_setprio(1);
        #pragma unroll
        for (int c2 = 0; c2 < 2; ++c2) {
            const bf16x8 paY = *reinterpret_cast<const bf16x8*>(
                plY + lr * 64 + ((c2 * 32 + lk) ^ swz));
            #pragma unroll
            for (int ni = 0; ni < 4; ++ni) {
                const bf16x8 av = *reinterpret_cast<const bf16x8*>(
                    vp + (size_t)(ni * 16 + lr) * S_LEN + kv0 + c2 * 32 + lk);
                accY[ni] = __builtin_amdgcn_mfma_f32_16x16x32_bf16(av, paY, accY[ni], 0, 0, 0);
            }
        }
        __builtin_amdgcn_s_setprio(0);
    }

    // ---- epilogue: lane's q-row = qw + lr; e = ni*16 + lg*4 + r ----
    const float livX = 1.0f / lX;
    const float livY = 1.0f / lY;
    float* orX = out + (size_t)(bq * S_LEN + qwx + lr) * D_DIM + hq * HDIM;
    float* orY = out + (size_t)(bq * S_LEN + qwy + lr) * D_DIM + hq * HDIM;
    #pragma unroll
    for (int ni = 0; ni < 4; ++ni) {
        f32x4 ox, oy;
        #pragma unroll
        for (int r = 0; r < 4; ++r) {
            ox[r] = accX[ni][r] * livX;
            oy[r] = accY[ni][r] * livY;
        }
        *reinterpret_cast<f32x4*>(orX + ni * 16 + lg * 4) = ox;
        *reinterpret_cast<f32x4*>(orY + ni * 16 + lg * 4) = oy;
    }
}

extern "C" void kernel_launch(void* const* d_in, const int* in_sizes, int n_in,
                              void* d_out, int out_size, void* d_ws, size_t ws_size,
                              hipStream_t stream)
{
    const float* x  = (const float*)d_in[0];
    const float* Wq = (const float*)d_in[1];
    const float* Wk = (const float*)d_in[2];
    const float* Wv = (const float*)d_in[3];
    float* out = (float*)d_out;

    const size_t x_elems = (size_t)BATCH * S_LEN * D_DIM;
    const size_t w_elems = (size_t)D_DIM * D_DIM;
    __bf16* xb   = (__bf16*)d_out;          // scratch in d_out (overwritten)
    __bf16* wcat = xb + x_elems;

    const size_t per_buf = (size_t)BATCH * NHEAD * S_LEN * HDIM;
    __bf16* qb = (__bf16*)d_ws;
    __bf16* kb = qb + per_buf;
    __bf16* vb = kb + per_buf;

    cvt_kernel<<<(int)(x_elems / 8 / 256), 256, 0, stream>>>(x, xb, (int)(x_elems / 8));
    cvt_kernel<<<(int)(w_elems / 8 / 256), 256, 0, stream>>>(Wq, wcat, (int)(w_elems / 8));
    cvt_kernel<<<(int)(w_elems / 8 / 256), 256, 0, stream>>>(Wk, wcat + w_elems, (int)(w_elems / 8));
    cvt_kernel<<<(int)(w_elems / 8 / 256), 256, 0, stream>>>(Wv, wcat + 2 * w_elems, (int)(w_elems / 8));

    dim3 grid1(3 * D_DIM / 128, (BATCH * S_LEN) / 128);   // (24, 64)
    proj_gemm_kernel<<<grid1, dim3(256), 0, stream>>>(xb, wcat, qb, kb, vb);

    attn_kernel<<<dim3(4096), dim3(64), 0, stream>>>(qb, kb, vb, out);
}